// Round 3
// baseline (1820.489 us; speedup 1.0000x reference)
//
#include <hip/hip_runtime.h>
#include <hip/hip_bf16.h>
#include <math.h>

#define B_  32
#define S_  2048
#define H_  1024
#define M_TOT (B_ * S_)   // 65536 rows

typedef __bf16 bf16x8 __attribute__((ext_vector_type(8)));
typedef float  f32x4  __attribute__((ext_vector_type(4)));
typedef unsigned short ushort8 __attribute__((ext_vector_type(8)));

// f32 -> bf16 round-to-nearest-even
__device__ __forceinline__ unsigned short f2bf(float f) {
    union { float f; unsigned int u; } v; v.f = f;
    unsigned int u = v.u;
    return (unsigned short)((u + 0x7fffu + ((u >> 16) & 1u)) >> 16);
}

__device__ __forceinline__ float bf2f(unsigned short s) {
    return __uint_as_float(((unsigned int)s) << 16);
}

// tanh via exp: ~6 VALU insts, saturates correctly
__device__ __forceinline__ float fast_tanh(float x) {
    float e = __expf(2.0f * x);
    return 1.0f - 2.0f / (e + 1.0f);
}

// ---------------------------------------------------------------------------
// Kernel 1: mean over s + f32->bf16 convert. grid (32 b, 64 sc of 32 rows).
// ---------------------------------------------------------------------------
__global__ void k_meanconv(const float* __restrict__ x,
                           unsigned short* __restrict__ xbf,
                           float* __restrict__ meanOut /* pre-zeroed */) {
    int b  = blockIdx.x;
    int sc = blockIdx.y;
    int t  = threadIdx.x;
    size_t base = ((size_t)b * S_ + (size_t)sc * 32) * H_;
    const float4* xr = (const float4*)(x + base);
    ushort4* xo = (ushort4*)(xbf + base);
    float a0 = 0.f, a1 = 0.f, a2 = 0.f, a3 = 0.f;
    for (int s = 0; s < 32; ++s) {
        float4 v = xr[(size_t)s * 256 + t];
        a0 += v.x; a1 += v.y; a2 += v.z; a3 += v.w;
        ushort4 o;
        o.x = f2bf(v.x); o.y = f2bf(v.y); o.z = f2bf(v.z); o.w = f2bf(v.w);
        xo[(size_t)s * 256 + t] = o;
    }
    const float scl = 1.0f / (float)S_;
    float* mp = meanOut + b * H_ + t * 4;
    atomicAdd(mp + 0, a0 * scl);
    atomicAdd(mp + 1, a1 * scl);
    atomicAdd(mp + 2, a2 * scl);
    atomicAdd(mp + 3, a3 * scl);
}

// ---------------------------------------------------------------------------
// Kernel 2: W -> bf16 transposed via LDS tile (coalesced both sides).
// grid (16 kt, 16 nt, 2 hop), block 256.  WT[hop*1024 + n][k] = W[k][n]
// ---------------------------------------------------------------------------
__global__ void k_wconv(const float* __restrict__ W1,
                        const float* __restrict__ W2,
                        unsigned short* __restrict__ WT) {
    __shared__ float tile[64][65];   // +1 pad: conflict-free column reads
    int kt = blockIdx.x * 64;
    int nt = blockIdx.y * 64;
    const float* W = blockIdx.z ? W2 : W1;
    int t = threadIdx.x;
    int r  = t >> 4;           // 0..15
    int c4 = (t & 15) * 4;     // 0,4,..,60
#pragma unroll
    for (int i = 0; i < 4; ++i) {
        float4 v = *(const float4*)(W + (size_t)(kt + r + i * 16) * H_ + nt + c4);
        tile[r + i * 16][c4 + 0] = v.x;
        tile[r + i * 16][c4 + 1] = v.y;
        tile[r + i * 16][c4 + 2] = v.z;
        tile[r + i * 16][c4 + 3] = v.w;
    }
    __syncthreads();
    int n  = t & 63;           // output row within tile
    int kg = (t >> 6) * 16;    // 16 k per thread
    unsigned short* dst = WT + (size_t)(blockIdx.z * H_ + nt + n) * H_ + kt + kg;
#pragma unroll
    for (int jj = 0; jj < 4; ++jj) {
        ushort4 o;
        o.x = f2bf(tile[kg + jj * 4 + 0][n]);
        o.y = f2bf(tile[kg + jj * 4 + 1][n]);
        o.z = f2bf(tile[kg + jj * 4 + 2][n]);
        o.w = f2bf(tile[kg + jj * 4 + 3][n]);
        *(ushort4*)(dst + jj * 4) = o;
    }
}

// ---------------------------------------------------------------------------
// Kernel 3a: partial (m_hop[b] @ Wm) over an H-chunk -> atomicAdd into vtmp
//   m_0 = mean*q ;  m_1 = 2*mean*q.   grid (32 b, 2 hop, 8 hc), block 256.
// ---------------------------------------------------------------------------
__global__ void k_vpart(const float* __restrict__ meanIn,
                        const float* __restrict__ q,
                        const float* __restrict__ Wm1,
                        const float* __restrict__ Wm2,
                        float* __restrict__ vtmp /* pre-zeroed */) {
    int b   = blockIdx.x;
    int hop = blockIdx.y;
    int hc  = blockIdx.z;
    int t   = threadIdx.x;
    __shared__ float mL[128];
    float scale = (hop == 0) ? 1.0f : 2.0f;
    int h0 = hc * 128;
    if (t < 128)
        mL[t] = meanIn[b * H_ + h0 + t] * q[b * H_ + h0 + t] * scale;
    __syncthreads();
    const float* Wm = hop ? Wm2 : Wm1;
    int d0 = t * 4;
    float a0 = 0.f, a1 = 0.f, a2 = 0.f, a3 = 0.f;
    for (int h = 0; h < 128; ++h) {
        float m = mL[h];
        float4 w = *(const float4*)(Wm + (size_t)(h0 + h) * H_ + d0);
        a0 += m * w.x; a1 += m * w.y; a2 += m * w.z; a3 += m * w.w;
    }
    float* vo = vtmp + b * 2048 + hop * H_ + d0;
    atomicAdd(vo + 0, a0);
    atomicAdd(vo + 1, a1);
    atomicAdd(vo + 2, a2);
    atomicAdd(vo + 3, a3);
}

// Kernel 3b: vcat = tanh(vtmp) * Wh.  grid 256, block 256.
__global__ void k_vfin(const float* __restrict__ vtmp,
                       const float* __restrict__ Wh1,
                       const float* __restrict__ Wh2,
                       float* __restrict__ vcat) {
    int i = blockIdx.x * 256 + threadIdx.x;   // [0, 65536)
    int hop = (i >> 10) & 1;
    int d = i & 1023;
    const float* Wh = hop ? Wh2 : Wh1;
    vcat[i] = tanhf(vtmp[i]) * Wh[d];
}

// ---------------------------------------------------------------------------
// Kernel 4: fused GEMM  P = Xbf @ WT^T (M=65536, N=2048, K=1024), bf16 MFMA
//   epilogue: U[hop][row] += sum_n fast_tanh(P[row,n]) * vcat[b,n]
// BK=64 (32 KB LDS): 16 barrier pairs instead of 32; 8 global_load_lds
// queued per drain. LDS swizzle: chunk (row, c) at slot (c+row)&7 within the
// row's 128 B -> fragment b128 reads hit the 8-cycle minimum, zero conflicts.
// ---------------------------------------------------------------------------
__global__ __launch_bounds__(256, 5) void k_gemm(const unsigned short* __restrict__ Xbf,
                                                 const unsigned short* __restrict__ WT,
                                                 const float* __restrict__ vcat,
                                                 float* __restrict__ U /* pre-zeroed */) {
    int nt = blockIdx.x;           // 0..15
    int mt = blockIdx.y;           // 0..511
    int m0 = mt * 128;
    int n0 = nt * 128;
    int t    = threadIdx.x;
    int lane = t & 63;
    int wave = t >> 6;
    int wm = wave >> 1, wn = wave & 1;
    int fr = lane & 15;            // fragment row within 16
    int fq = lane >> 4;            // quad 0..3 (k-chunk within a 32-k step)

    __shared__ unsigned short As[128 * 64];
    __shared__ unsigned short Bs[128 * 64];

    f32x4 acc[4][4];
#pragma unroll
    for (int i = 0; i < 4; ++i)
#pragma unroll
        for (int j = 0; j < 4; ++j)
#pragma unroll
            for (int r = 0; r < 4; ++r) acc[i][j][r] = 0.0f;

    // staging: lane-slot idx = row*8 + slot; slot holds global chunk
    // kc = (slot - row) & 7  (swizzle inverse). 4 slots per thread per matrix.
    const unsigned short* gA[4];
    const unsigned short* gB[4];
    unsigned short* lA[4];
    unsigned short* lB[4];
#pragma unroll
    for (int j = 0; j < 4; ++j) {
        int idx = t + 256 * j;
        int row = idx >> 3;
        int kc  = ((idx & 7) - row) & 7;
        gA[j] = Xbf + (size_t)(m0 + row) * H_ + kc * 8;
        gB[j] = WT  + (size_t)(n0 + row) * H_ + kc * 8;
        lA[j] = As + idx * 8;
        lB[j] = Bs + idx * 8;
    }

    // fragment pointers: row = wtile + i*16 + fr; chunk c = kk*4 + fq;
    // slot = (c + row) & 7 = (c + fr) & 7  (tile offsets ≡ 0 mod 8)
    const bf16x8* pa[2][4];
    const bf16x8* pb[2][4];
#pragma unroll
    for (int kk = 0; kk < 2; ++kk) {
        int slot = ((kk * 4 + fq) + fr) & 7;
#pragma unroll
        for (int i = 0; i < 4; ++i)
            pa[kk][i] = (const bf16x8*)(As + (wm * 64 + i * 16 + fr) * 64 + slot * 8);
#pragma unroll
        for (int j = 0; j < 4; ++j)
            pb[kk][j] = (const bf16x8*)(Bs + (wn * 64 + j * 16 + fr) * 64 + slot * 8);
    }

    for (int k0 = 0; k0 < H_; k0 += 64) {
#pragma unroll
        for (int j = 0; j < 4; ++j) {
            __builtin_amdgcn_global_load_lds((const __attribute__((address_space(1))) void*)(gA[j] + k0),
                                             (__attribute__((address_space(3))) void*)lA[j], 16, 0, 0);
            __builtin_amdgcn_global_load_lds((const __attribute__((address_space(1))) void*)(gB[j] + k0),
                                             (__attribute__((address_space(3))) void*)lB[j], 16, 0, 0);
        }
        __syncthreads();   // drains vmcnt (staging complete)
#pragma unroll
        for (int kk = 0; kk < 2; ++kk) {
            bf16x8 af[4], bg[4];
#pragma unroll
            for (int i = 0; i < 4; ++i) af[i] = *pa[kk][i];
#pragma unroll
            for (int j = 0; j < 4; ++j) bg[j] = *pb[kk][j];
#pragma unroll
            for (int i = 0; i < 4; ++i)
#pragma unroll
                for (int j = 0; j < 4; ++j)
                    acc[i][j] = __builtin_amdgcn_mfma_f32_16x16x32_bf16(af[i], bg[j], acc[i][j], 0, 0, 0);
        }
        __syncthreads();   // protect LDS before next stage overwrites
    }

    // epilogue: tanh, weight by v, reduce 128 columns of this block
    int b   = m0 >> 11;            // 2048 rows per batch; tiles never straddle b
    int hop = n0 >> 10;
    float vv[4];
#pragma unroll
    for (int j = 0; j < 4; ++j)
        vv[j] = vcat[b * 2048 + n0 + wn * 64 + j * 16 + fr];

#pragma unroll
    for (int i = 0; i < 4; ++i) {
#pragma unroll
        for (int r = 0; r < 4; ++r) {
            float sum = fast_tanh(acc[i][0][r]) * vv[0]
                      + fast_tanh(acc[i][1][r]) * vv[1]
                      + fast_tanh(acc[i][2][r]) * vv[2]
                      + fast_tanh(acc[i][3][r]) * vv[3];
            sum += __shfl_xor(sum, 1);
            sum += __shfl_xor(sum, 2);
            sum += __shfl_xor(sum, 4);
            sum += __shfl_xor(sum, 8);
            if (fr == 0) {
                int row = m0 + wm * 64 + i * 16 + fq * 4 + r;
                atomicAdd(&U[(size_t)hop * M_TOT + row], sum);
            }
        }
    }
}

// ---------------------------------------------------------------------------
// Kernel 5: softmax over s per (b,hop).  grid 64, block 256.
// ---------------------------------------------------------------------------
__global__ void k_softmax(const float* __restrict__ U, float* __restrict__ alpha) {
    int id  = blockIdx.x;
    int hop = id >> 5, b = id & 31;
    int t = threadIdx.x;
    const float* u = U + (size_t)hop * M_TOT + (size_t)b * S_;
    float* al = alpha + (size_t)hop * M_TOT + (size_t)b * S_;
    float v[8];
    float mx = -1e30f;
#pragma unroll
    for (int i = 0; i < 8; ++i) { v[i] = u[t + i * 256]; mx = fmaxf(mx, v[i]); }
    __shared__ float red[256];
    red[t] = mx; __syncthreads();
    for (int s = 128; s > 0; s >>= 1) {
        if (t < s) red[t] = fmaxf(red[t], red[t + s]);
        __syncthreads();
    }
    mx = red[0]; __syncthreads();
    float sum = 0.f;
#pragma unroll
    for (int i = 0; i < 8; ++i) { v[i] = expf(v[i] - mx); sum += v[i]; }
    red[t] = sum; __syncthreads();
    for (int s = 128; s > 0; s >>= 1) {
        if (t < s) red[t] += red[t + s];
        __syncthreads();
    }
    float inv = 1.0f / red[0];
#pragma unroll
    for (int i = 0; i < 8; ++i) al[t + i * 256] = v[i] * inv;
}

// ---------------------------------------------------------------------------
// Kernel 6: u_att = sum_s inputs[b,s,:] * alpha[b,s].
// grid (32 b, 64 sc of 32 rows), block 128 (each thread: 8 cols, 16B loads).
// ---------------------------------------------------------------------------
__global__ void k_wsum(const unsigned short* __restrict__ Xbf,
                       const float* __restrict__ alpha,
                       float* __restrict__ out1 /* pre-zeroed */,
                       float* __restrict__ out2 /* pre-zeroed */) {
    int b  = blockIdx.x;
    int sc = blockIdx.y;
    int t  = threadIdx.x;   // 0..127
    __shared__ float a1[32], a2[32];
    int s0 = sc * 32;
    if (t < 32)       a1[t]      = alpha[(size_t)b * S_ + s0 + t];
    else if (t < 64)  a2[t - 32] = alpha[(size_t)M_TOT + (size_t)b * S_ + s0 + (t - 32)];
    __syncthreads();
    const ushort8* xr = (const ushort8*)(Xbf + ((size_t)b * S_ + s0) * H_);
    float acc1[8], acc2[8];
#pragma unroll
    for (int e = 0; e < 8; ++e) { acc1[e] = 0.f; acc2[e] = 0.f; }
    for (int s = 0; s < 32; ++s) {
        ushort8 u = xr[(size_t)s * 128 + t];
        float w1 = a1[s], w2 = a2[s];
#pragma unroll
        for (int e = 0; e < 8; ++e) {
            float f = bf2f(u[e]);
            acc1[e] += f * w1;
            acc2[e] += f * w2;
        }
    }
    float* o1 = out1 + b * H_ + t * 8;
    float* o2 = out2 + b * H_ + t * 8;
#pragma unroll
    for (int e = 0; e < 8; ++e) {
        atomicAdd(o1 + e, acc1[e]);
        atomicAdd(o2 + e, acc2[e]);
    }
}

// ---------------------------------------------------------------------------
extern "C" void kernel_launch(void* const* d_in, const int* in_sizes, int n_in,
                              void* d_out, int out_size, void* d_ws, size_t ws_size,
                              hipStream_t stream) {
    const float* inputs = (const float*)d_in[0];
    const float* q      = (const float*)d_in[1];
    const float* W1     = (const float*)d_in[2];
    const float* Wm1    = (const float*)d_in[3];
    const float* Wh1    = (const float*)d_in[4];
    const float* W2     = (const float*)d_in[5];
    const float* Wm2    = (const float*)d_in[6];
    const float* Wh2    = (const float*)d_in[7];
    float* out = (float*)d_out;     // [3,B,H]: mean | u_att1 | u_att2

    // workspace layout (bytes); total ~133.8 MiB
    char* ws = (char*)d_ws;
    unsigned short* Xbf  = (unsigned short*)(ws);                 // 134217728 B
    unsigned short* WT   = (unsigned short*)(ws + 134217728);     //   4194304 B
    float*          vcat = (float*)(ws + 138412032);              //    262144 B
    float*          U    = (float*)(ws + 138674176);              //    524288 B
    float*          alph = (float*)(ws + 139198464);              //    524288 B
    float*          vtmp = (float*)(ws + 139722752);              //    262144 B

    hipMemsetAsync(d_out, 0, (size_t)out_size * sizeof(float), stream);
    // zero U + alph + vtmp in one shot (contiguous region)
    hipMemsetAsync(U, 0, 524288 + 524288 + 262144, stream);

    k_meanconv<<<dim3(32, 64),    256, 0, stream>>>(inputs, Xbf, out);
    k_wconv  <<<dim3(16, 16, 2),  256, 0, stream>>>(W1, W2, WT);
    k_vpart  <<<dim3(32, 2, 8),   256, 0, stream>>>(out, q, Wm1, Wm2, vtmp);
    k_vfin   <<<dim3(256),        256, 0, stream>>>(vtmp, Wh1, Wh2, vcat);
    k_gemm   <<<dim3(16, 512),    256, 0, stream>>>(Xbf, WT, vcat, U);
    k_softmax<<<dim3(64),         256, 0, stream>>>(U, alph);
    k_wsum   <<<dim3(32, 64),     128, 0, stream>>>(Xbf, alph, out + 32768, out + 65536);
}

// Round 4
// 1035.255 us; speedup vs baseline: 1.7585x; 1.7585x over previous
//
#include <hip/hip_runtime.h>
#include <hip/hip_bf16.h>
#include <math.h>

#define B_  32
#define S_  2048
#define H_  1024
#define M_TOT (B_ * S_)   // 65536 rows

typedef __bf16 bf16x8 __attribute__((ext_vector_type(8)));
typedef float  f32x4  __attribute__((ext_vector_type(4)));
typedef unsigned short ushort8 __attribute__((ext_vector_type(8)));

// f32 -> bf16 round-to-nearest-even
__device__ __forceinline__ unsigned short f2bf(float f) {
    union { float f; unsigned int u; } v; v.f = f;
    unsigned int u = v.u;
    return (unsigned short)((u + 0x7fffu + ((u >> 16) & 1u)) >> 16);
}

__device__ __forceinline__ float bf2f(unsigned short s) {
    return __uint_as_float(((unsigned int)s) << 16);
}

// tanh via exp: ~6 VALU insts, saturates correctly
__device__ __forceinline__ float fast_tanh(float x) {
    float e = __expf(2.0f * x);
    return 1.0f - 2.0f / (e + 1.0f);
}

// ---------------------------------------------------------------------------
// Kernel 1: mean over s + f32->bf16 convert. grid (32 b, 64 sc of 32 rows).
// ---------------------------------------------------------------------------
__global__ void k_meanconv(const float* __restrict__ x,
                           unsigned short* __restrict__ xbf,
                           float* __restrict__ meanOut /* pre-zeroed */) {
    int b  = blockIdx.x;
    int sc = blockIdx.y;
    int t  = threadIdx.x;
    size_t base = ((size_t)b * S_ + (size_t)sc * 32) * H_;
    const float4* xr = (const float4*)(x + base);
    ushort4* xo = (ushort4*)(xbf + base);
    float a0 = 0.f, a1 = 0.f, a2 = 0.f, a3 = 0.f;
    for (int s = 0; s < 32; ++s) {
        float4 v = xr[(size_t)s * 256 + t];
        a0 += v.x; a1 += v.y; a2 += v.z; a3 += v.w;
        ushort4 o;
        o.x = f2bf(v.x); o.y = f2bf(v.y); o.z = f2bf(v.z); o.w = f2bf(v.w);
        xo[(size_t)s * 256 + t] = o;
    }
    const float scl = 1.0f / (float)S_;
    float* mp = meanOut + b * H_ + t * 4;
    atomicAdd(mp + 0, a0 * scl);
    atomicAdd(mp + 1, a1 * scl);
    atomicAdd(mp + 2, a2 * scl);
    atomicAdd(mp + 3, a3 * scl);
}

// ---------------------------------------------------------------------------
// Kernel 2: W -> bf16 transposed via LDS tile (coalesced both sides).
// grid (16 kt, 16 nt, 2 hop), block 256.  WT[hop*1024 + n][k] = W[k][n]
// ---------------------------------------------------------------------------
__global__ void k_wconv(const float* __restrict__ W1,
                        const float* __restrict__ W2,
                        unsigned short* __restrict__ WT) {
    __shared__ float tile[64][65];   // +1 pad: conflict-free column reads
    int kt = blockIdx.x * 64;
    int nt = blockIdx.y * 64;
    const float* W = blockIdx.z ? W2 : W1;
    int t = threadIdx.x;
    int r  = t >> 4;           // 0..15
    int c4 = (t & 15) * 4;     // 0,4,..,60
#pragma unroll
    for (int i = 0; i < 4; ++i) {
        float4 v = *(const float4*)(W + (size_t)(kt + r + i * 16) * H_ + nt + c4);
        tile[r + i * 16][c4 + 0] = v.x;
        tile[r + i * 16][c4 + 1] = v.y;
        tile[r + i * 16][c4 + 2] = v.z;
        tile[r + i * 16][c4 + 3] = v.w;
    }
    __syncthreads();
    int n  = t & 63;           // output row within tile
    int kg = (t >> 6) * 16;    // 16 k per thread
    unsigned short* dst = WT + (size_t)(blockIdx.z * H_ + nt + n) * H_ + kt + kg;
#pragma unroll
    for (int jj = 0; jj < 4; ++jj) {
        ushort4 o;
        o.x = f2bf(tile[kg + jj * 4 + 0][n]);
        o.y = f2bf(tile[kg + jj * 4 + 1][n]);
        o.z = f2bf(tile[kg + jj * 4 + 2][n]);
        o.w = f2bf(tile[kg + jj * 4 + 3][n]);
        *(ushort4*)(dst + jj * 4) = o;
    }
}

// ---------------------------------------------------------------------------
// Kernel 3a: partial (m_hop[b] @ Wm) over an H-chunk -> atomicAdd into vtmp
//   m_0 = mean*q ;  m_1 = 2*mean*q.   grid (32 b, 2 hop, 8 hc), block 256.
// ---------------------------------------------------------------------------
__global__ void k_vpart(const float* __restrict__ meanIn,
                        const float* __restrict__ q,
                        const float* __restrict__ Wm1,
                        const float* __restrict__ Wm2,
                        float* __restrict__ vtmp /* pre-zeroed */) {
    int b   = blockIdx.x;
    int hop = blockIdx.y;
    int hc  = blockIdx.z;
    int t   = threadIdx.x;
    __shared__ float mL[128];
    float scale = (hop == 0) ? 1.0f : 2.0f;
    int h0 = hc * 128;
    if (t < 128)
        mL[t] = meanIn[b * H_ + h0 + t] * q[b * H_ + h0 + t] * scale;
    __syncthreads();
    const float* Wm = hop ? Wm2 : Wm1;
    int d0 = t * 4;
    float a0 = 0.f, a1 = 0.f, a2 = 0.f, a3 = 0.f;
    for (int h = 0; h < 128; ++h) {
        float m = mL[h];
        float4 w = *(const float4*)(Wm + (size_t)(h0 + h) * H_ + d0);
        a0 += m * w.x; a1 += m * w.y; a2 += m * w.z; a3 += m * w.w;
    }
    float* vo = vtmp + b * 2048 + hop * H_ + d0;
    atomicAdd(vo + 0, a0);
    atomicAdd(vo + 1, a1);
    atomicAdd(vo + 2, a2);
    atomicAdd(vo + 3, a3);
}

// Kernel 3b: vcat = tanh(vtmp) * Wh.  grid 256, block 256.
__global__ void k_vfin(const float* __restrict__ vtmp,
                       const float* __restrict__ Wh1,
                       const float* __restrict__ Wh2,
                       float* __restrict__ vcat) {
    int i = blockIdx.x * 256 + threadIdx.x;   // [0, 65536)
    int hop = (i >> 10) & 1;
    int d = i & 1023;
    const float* Wh = hop ? Wh2 : Wh1;
    vcat[i] = tanhf(vtmp[i]) * Wh[d];
}

// ---------------------------------------------------------------------------
// Kernel 4: fused GEMM  P = Xbf @ WT^T (M=65536, N=2048, K=1024), bf16 MFMA
//   epilogue: U[hop][row] += sum_n fast_tanh(P[row,n]) * vcat[b,n]
// BK=64 (32 KB LDS), 16 barrier pairs. PLAIN launch bounds: round-3's
// (256,5) forced VGPR to 48 -> acc spilled to scratch -> 4.7 GB HBM traffic.
// LDS swizzle: chunk (row,c) at slot (c+row)&7 within the row's 128 B.
// ---------------------------------------------------------------------------
__global__ __launch_bounds__(256) void k_gemm(const unsigned short* __restrict__ Xbf,
                                              const unsigned short* __restrict__ WT,
                                              const float* __restrict__ vcat,
                                              float* __restrict__ U /* pre-zeroed */) {
    int nt = blockIdx.x;           // 0..15
    int mt = blockIdx.y;           // 0..511
    int m0 = mt * 128;
    int n0 = nt * 128;
    int t    = threadIdx.x;
    int lane = t & 63;
    int wave = t >> 6;
    int wm = wave >> 1, wn = wave & 1;
    int fr = lane & 15;            // fragment row within 16
    int fq = lane >> 4;            // quad 0..3 (k-chunk within a 32-k step)

    __shared__ unsigned short As[128 * 64];
    __shared__ unsigned short Bs[128 * 64];

    f32x4 acc[4][4];
#pragma unroll
    for (int i = 0; i < 4; ++i)
#pragma unroll
        for (int j = 0; j < 4; ++j)
#pragma unroll
            for (int r = 0; r < 4; ++r) acc[i][j][r] = 0.0f;

    // wave-uniform global bases (SGPRs) + shared lane offsets (A/B identical)
    const unsigned short* Abase = Xbf + (size_t)m0 * H_;
    const unsigned short* Bbase = WT  + (size_t)n0 * H_;
    int off[4];                    // row*H + kc*8, lane-dependent, k0-invariant
#pragma unroll
    for (int j = 0; j < 4; ++j) {
        int idx = t + 256 * j;
        int row = idx >> 3;
        int kc  = ((idx & 7) - row) & 7;
        off[j] = row * H_ + kc * 8;
    }

    // fragment offsets (shorts) for kk=0; kk=1 slot = slot0 ^ 4 -> +/-64 B
    int slot0 = (fq + fr) & 7;
    int dOff  = ((slot0 ^ 4) - slot0) * 8;   // +32 or -32 shorts
    int frA[4], frB[4];
#pragma unroll
    for (int i = 0; i < 4; ++i) {
        frA[i] = (wm * 64 + i * 16 + fr) * 64 + slot0 * 8;
        frB[i] = (wn * 64 + i * 16 + fr) * 64 + slot0 * 8;
    }

    for (int k0 = 0; k0 < H_; k0 += 64) {
#pragma unroll
        for (int j = 0; j < 4; ++j) {
            __builtin_amdgcn_global_load_lds((const __attribute__((address_space(1))) void*)(Abase + off[j] + k0),
                                             (__attribute__((address_space(3))) void*)(As + (t + 256 * j) * 8), 16, 0, 0);
            __builtin_amdgcn_global_load_lds((const __attribute__((address_space(1))) void*)(Bbase + off[j] + k0),
                                             (__attribute__((address_space(3))) void*)(Bs + (t + 256 * j) * 8), 16, 0, 0);
        }
        __syncthreads();   // drains vmcnt (staging complete)
#pragma unroll
        for (int kk = 0; kk < 2; ++kk) {
            int d = kk ? dOff : 0;
            bf16x8 af[4], bg[4];
#pragma unroll
            for (int i = 0; i < 4; ++i) af[i] = *(const bf16x8*)(As + frA[i] + d);
#pragma unroll
            for (int j = 0; j < 4; ++j) bg[j] = *(const bf16x8*)(Bs + frB[j] + d);
#pragma unroll
            for (int i = 0; i < 4; ++i)
#pragma unroll
                for (int j = 0; j < 4; ++j)
                    acc[i][j] = __builtin_amdgcn_mfma_f32_16x16x32_bf16(af[i], bg[j], acc[i][j], 0, 0, 0);
        }
        __syncthreads();   // protect LDS before next stage overwrites
    }

    // epilogue: tanh, weight by v, reduce 128 columns of this block
    int b   = m0 >> 11;            // 2048 rows per batch; tiles never straddle b
    int hop = n0 >> 10;
    float vv[4];
#pragma unroll
    for (int j = 0; j < 4; ++j)
        vv[j] = vcat[b * 2048 + n0 + wn * 64 + j * 16 + fr];

#pragma unroll
    for (int i = 0; i < 4; ++i) {
#pragma unroll
        for (int r = 0; r < 4; ++r) {
            float sum = fast_tanh(acc[i][0][r]) * vv[0]
                      + fast_tanh(acc[i][1][r]) * vv[1]
                      + fast_tanh(acc[i][2][r]) * vv[2]
                      + fast_tanh(acc[i][3][r]) * vv[3];
            sum += __shfl_xor(sum, 1);
            sum += __shfl_xor(sum, 2);
            sum += __shfl_xor(sum, 4);
            sum += __shfl_xor(sum, 8);
            if (fr == 0) {
                int row = m0 + wm * 64 + i * 16 + fq * 4 + r;
                atomicAdd(&U[(size_t)hop * M_TOT + row], sum);
            }
        }
    }
}

// ---------------------------------------------------------------------------
// Kernel 5: softmax over s per (b,hop).  grid 64, block 256.
// ---------------------------------------------------------------------------
__global__ void k_softmax(const float* __restrict__ U, float* __restrict__ alpha) {
    int id  = blockIdx.x;
    int hop = id >> 5, b = id & 31;
    int t = threadIdx.x;
    const float* u = U + (size_t)hop * M_TOT + (size_t)b * S_;
    float* al = alpha + (size_t)hop * M_TOT + (size_t)b * S_;
    float v[8];
    float mx = -1e30f;
#pragma unroll
    for (int i = 0; i < 8; ++i) { v[i] = u[t + i * 256]; mx = fmaxf(mx, v[i]); }
    __shared__ float red[256];
    red[t] = mx; __syncthreads();
    for (int s = 128; s > 0; s >>= 1) {
        if (t < s) red[t] = fmaxf(red[t], red[t + s]);
        __syncthreads();
    }
    mx = red[0]; __syncthreads();
    float sum = 0.f;
#pragma unroll
    for (int i = 0; i < 8; ++i) { v[i] = expf(v[i] - mx); sum += v[i]; }
    red[t] = sum; __syncthreads();
    for (int s = 128; s > 0; s >>= 1) {
        if (t < s) red[t] += red[t + s];
        __syncthreads();
    }
    float inv = 1.0f / red[0];
#pragma unroll
    for (int i = 0; i < 8; ++i) al[t + i * 256] = v[i] * inv;
}

// ---------------------------------------------------------------------------
// Kernel 6: u_att = sum_s inputs[b,s,:] * alpha[b,s].
// grid (32 b, 64 sc of 32 rows), block 128 (each thread: 8 cols, 16B loads).
// ---------------------------------------------------------------------------
__global__ void k_wsum(const unsigned short* __restrict__ Xbf,
                       const float* __restrict__ alpha,
                       float* __restrict__ out1 /* pre-zeroed */,
                       float* __restrict__ out2 /* pre-zeroed */) {
    int b  = blockIdx.x;
    int sc = blockIdx.y;
    int t  = threadIdx.x;   // 0..127
    __shared__ float a1[32], a2[32];
    int s0 = sc * 32;
    if (t < 32)       a1[t]      = alpha[(size_t)b * S_ + s0 + t];
    else if (t < 64)  a2[t - 32] = alpha[(size_t)M_TOT + (size_t)b * S_ + s0 + (t - 32)];
    __syncthreads();
    const ushort8* xr = (const ushort8*)(Xbf + ((size_t)b * S_ + s0) * H_);
    float acc1[8], acc2[8];
#pragma unroll
    for (int e = 0; e < 8; ++e) { acc1[e] = 0.f; acc2[e] = 0.f; }
    for (int s = 0; s < 32; ++s) {
        ushort8 u = xr[(size_t)s * 128 + t];
        float w1 = a1[s], w2 = a2[s];
#pragma unroll
        for (int e = 0; e < 8; ++e) {
            float f = bf2f(u[e]);
            acc1[e] += f * w1;
            acc2[e] += f * w2;
        }
    }
    float* o1 = out1 + b * H_ + t * 8;
    float* o2 = out2 + b * H_ + t * 8;
#pragma unroll
    for (int e = 0; e < 8; ++e) {
        atomicAdd(o1 + e, acc1[e]);
        atomicAdd(o2 + e, acc2[e]);
    }
}

// ---------------------------------------------------------------------------
extern "C" void kernel_launch(void* const* d_in, const int* in_sizes, int n_in,
                              void* d_out, int out_size, void* d_ws, size_t ws_size,
                              hipStream_t stream) {
    const float* inputs = (const float*)d_in[0];
    const float* q      = (const float*)d_in[1];
    const float* W1     = (const float*)d_in[2];
    const float* Wm1    = (const float*)d_in[3];
    const float* Wh1    = (const float*)d_in[4];
    const float* W2     = (const float*)d_in[5];
    const float* Wm2    = (const float*)d_in[6];
    const float* Wh2    = (const float*)d_in[7];
    float* out = (float*)d_out;     // [3,B,H]: mean | u_att1 | u_att2

    // workspace layout (bytes); total ~133.8 MiB
    char* ws = (char*)d_ws;
    unsigned short* Xbf  = (unsigned short*)(ws);                 // 134217728 B
    unsigned short* WT   = (unsigned short*)(ws + 134217728);     //   4194304 B
    float*          vcat = (float*)(ws + 138412032);              //    262144 B
    float*          U    = (float*)(ws + 138674176);              //    524288 B
    float*          alph = (float*)(ws + 139198464);              //    524288 B
    float*          vtmp = (float*)(ws + 139722752);              //    262144 B

    hipMemsetAsync(d_out, 0, (size_t)out_size * sizeof(float), stream);
    // zero U + alph + vtmp in one shot (contiguous region)
    hipMemsetAsync(U, 0, 524288 + 524288 + 262144, stream);

    k_meanconv<<<dim3(32, 64),    256, 0, stream>>>(inputs, Xbf, out);
    k_wconv  <<<dim3(16, 16, 2),  256, 0, stream>>>(W1, W2, WT);
    k_vpart  <<<dim3(32, 2, 8),   256, 0, stream>>>(out, q, Wm1, Wm2, vtmp);
    k_vfin   <<<dim3(256),        256, 0, stream>>>(vtmp, Wh1, Wh2, vcat);
    k_gemm   <<<dim3(16, 512),    256, 0, stream>>>(Xbf, WT, vcat, U);
    k_softmax<<<dim3(64),         256, 0, stream>>>(U, alph);
    k_wsum   <<<dim3(32, 64),     128, 0, stream>>>(Xbf, alph, out + 32768, out + 65536);
}

// Round 5
// 897.201 us; speedup vs baseline: 2.0291x; 1.1539x over previous
//
#include <hip/hip_runtime.h>
#include <hip/hip_bf16.h>
#include <math.h>

#define B_  32
#define S_  2048
#define H_  1024
#define M_TOT (B_ * S_)   // 65536 rows

typedef __bf16 bf16x8 __attribute__((ext_vector_type(8)));
typedef float  f32x4  __attribute__((ext_vector_type(4)));

// f32 -> bf16 round-to-nearest-even
__device__ __forceinline__ unsigned short f2bf(float f) {
    union { float f; unsigned int u; } v; v.f = f;
    unsigned int u = v.u;
    return (unsigned short)((u + 0x7fffu + ((u >> 16) & 1u)) >> 16);
}

__device__ __forceinline__ float bf2f(unsigned short s) {
    return __uint_as_float(((unsigned int)s) << 16);
}

// tanh via exp: ~6 VALU insts, saturates correctly
__device__ __forceinline__ float fast_tanh(float x) {
    float e = __expf(2.0f * x);
    return 1.0f - 2.0f / (e + 1.0f);
}

// ---------------------------------------------------------------------------
// Kernel 1: mean over s + f32->bf16 convert. grid (32 b, 64 sc of 32 rows).
// ---------------------------------------------------------------------------
__global__ void k_meanconv(const float* __restrict__ x,
                           unsigned short* __restrict__ xbf,
                           float* __restrict__ meanOut /* pre-zeroed */) {
    int b  = blockIdx.x;
    int sc = blockIdx.y;
    int t  = threadIdx.x;
    size_t base = ((size_t)b * S_ + (size_t)sc * 32) * H_;
    const float4* xr = (const float4*)(x + base);
    ushort4* xo = (ushort4*)(xbf + base);
    float a0 = 0.f, a1 = 0.f, a2 = 0.f, a3 = 0.f;
    for (int s = 0; s < 32; ++s) {
        float4 v = xr[(size_t)s * 256 + t];
        a0 += v.x; a1 += v.y; a2 += v.z; a3 += v.w;
        ushort4 o;
        o.x = f2bf(v.x); o.y = f2bf(v.y); o.z = f2bf(v.z); o.w = f2bf(v.w);
        xo[(size_t)s * 256 + t] = o;
    }
    const float scl = 1.0f / (float)S_;
    float* mp = meanOut + b * H_ + t * 4;
    atomicAdd(mp + 0, a0 * scl);
    atomicAdd(mp + 1, a1 * scl);
    atomicAdd(mp + 2, a2 * scl);
    atomicAdd(mp + 3, a3 * scl);
}

// ---------------------------------------------------------------------------
// Kernel 2: W -> bf16 transposed via LDS tile (coalesced both sides).
// grid (16 kt, 16 nt, 2 hop), block 256.  WT[hop*1024 + n][k] = W[k][n]
// ---------------------------------------------------------------------------
__global__ void k_wconv(const float* __restrict__ W1,
                        const float* __restrict__ W2,
                        unsigned short* __restrict__ WT) {
    __shared__ float tile[64][65];   // +1 pad: conflict-free column reads
    int kt = blockIdx.x * 64;
    int nt = blockIdx.y * 64;
    const float* W = blockIdx.z ? W2 : W1;
    int t = threadIdx.x;
    int r  = t >> 4;           // 0..15
    int c4 = (t & 15) * 4;     // 0,4,..,60
#pragma unroll
    for (int i = 0; i < 4; ++i) {
        float4 v = *(const float4*)(W + (size_t)(kt + r + i * 16) * H_ + nt + c4);
        tile[r + i * 16][c4 + 0] = v.x;
        tile[r + i * 16][c4 + 1] = v.y;
        tile[r + i * 16][c4 + 2] = v.z;
        tile[r + i * 16][c4 + 3] = v.w;
    }
    __syncthreads();
    int n  = t & 63;           // output row within tile
    int kg = (t >> 6) * 16;    // 16 k per thread
    unsigned short* dst = WT + (size_t)(blockIdx.z * H_ + nt + n) * H_ + kt + kg;
#pragma unroll
    for (int jj = 0; jj < 4; ++jj) {
        ushort4 o;
        o.x = f2bf(tile[kg + jj * 4 + 0][n]);
        o.y = f2bf(tile[kg + jj * 4 + 1][n]);
        o.z = f2bf(tile[kg + jj * 4 + 2][n]);
        o.w = f2bf(tile[kg + jj * 4 + 3][n]);
        *(ushort4*)(dst + jj * 4) = o;
    }
}

// ---------------------------------------------------------------------------
// Kernel 3a: partial (m_hop[b] @ Wm) over an H-chunk -> atomicAdd into vtmp
//   m_0 = mean*q ;  m_1 = 2*mean*q.   grid (32 b, 2 hop, 8 hc), block 256.
// ---------------------------------------------------------------------------
__global__ void k_vpart(const float* __restrict__ meanIn,
                        const float* __restrict__ q,
                        const float* __restrict__ Wm1,
                        const float* __restrict__ Wm2,
                        float* __restrict__ vtmp /* pre-zeroed */) {
    int b   = blockIdx.x;
    int hop = blockIdx.y;
    int hc  = blockIdx.z;
    int t   = threadIdx.x;
    __shared__ float mL[128];
    float scale = (hop == 0) ? 1.0f : 2.0f;
    int h0 = hc * 128;
    if (t < 128)
        mL[t] = meanIn[b * H_ + h0 + t] * q[b * H_ + h0 + t] * scale;
    __syncthreads();
    const float* Wm = hop ? Wm2 : Wm1;
    int d0 = t * 4;
    float a0 = 0.f, a1 = 0.f, a2 = 0.f, a3 = 0.f;
    for (int h = 0; h < 128; ++h) {
        float m = mL[h];
        float4 w = *(const float4*)(Wm + (size_t)(h0 + h) * H_ + d0);
        a0 += m * w.x; a1 += m * w.y; a2 += m * w.z; a3 += m * w.w;
    }
    float* vo = vtmp + b * 2048 + hop * H_ + d0;
    atomicAdd(vo + 0, a0);
    atomicAdd(vo + 1, a1);
    atomicAdd(vo + 2, a2);
    atomicAdd(vo + 3, a3);
}

// Kernel 3b: vcat = tanh(vtmp) * Wh.  grid 256, block 256.
__global__ void k_vfin(const float* __restrict__ vtmp,
                       const float* __restrict__ Wh1,
                       const float* __restrict__ Wh2,
                       float* __restrict__ vcat) {
    int i = blockIdx.x * 256 + threadIdx.x;   // [0, 65536)
    int hop = (i >> 10) & 1;
    int d = i & 1023;
    const float* Wh = hop ? Wh2 : Wh1;
    vcat[i] = tanhf(vtmp[i]) * Wh[d];
}

// ---------------------------------------------------------------------------
// Kernel 4: fused GEMM  P = Xbf @ WT^T (M=65536, N=2048, K=1024), bf16 MFMA
//   epilogue: U[hop][row] += sum_n fast_tanh(P[row,n]) * vcat[b,n]
// Round-2 proven structure: BK=32, 16 KB LDS, mod-4 swizzle, ~80 VGPR.
// NEW: 1-D grid with XCD-confined m-tiles — xcd=i&7 owns 64 consecutive mt,
// iterating all 16 nt per mt, so A-tiles stay in one XCD's L2 (15/16 reads
// become local L2 hits -> shorter vmcnt drain at the barrier).
// ---------------------------------------------------------------------------
__global__ __launch_bounds__(256) void k_gemm(const unsigned short* __restrict__ Xbf,
                                              const unsigned short* __restrict__ WT,
                                              const float* __restrict__ vcat,
                                              float* __restrict__ U /* pre-zeroed */) {
    int i = blockIdx.x;            // 0..8191
    int x = i & 7;                 // XCD slot (dispatch round-robin)
    int j = i >> 3;
    int nt = j & 15;               // n-tile fastest within an XCD's sequence
    int mt = x * 64 + (j >> 4);    // each XCD owns mt in [64x, 64x+64)
    int m0 = mt * 128;
    int n0 = nt * 128;
    int t    = threadIdx.x;
    int lane = t & 63;
    int wave = t >> 6;
    int wm = wave >> 1, wn = wave & 1;
    int fr = lane & 15;            // fragment row within 16
    int fq = lane >> 4;            // quad 0..3 (k-chunk)

    __shared__ unsigned short As[128 * 32];
    __shared__ unsigned short Bs[128 * 32];

    f32x4 acc[4][4];
#pragma unroll
    for (int i2 = 0; i2 < 4; ++i2)
#pragma unroll
        for (int j2 = 0; j2 < 4; ++j2)
#pragma unroll
            for (int r = 0; r < 4; ++r) acc[i2][j2][r] = 0.0f;

    // staging: lane idx covers (row = idx>>2, slot = idx&3); slot holds
    // global k-chunk kc = (slot - (row>>1)) & 3  (swizzle inverse)
    int idx0 = t, idx1 = t + 256;
    int row0 = idx0 >> 2, kc0 = ((idx0 & 3) - ((row0 >> 1) & 3)) & 3;
    int row1 = idx1 >> 2, kc1 = ((idx1 & 3) - ((row1 >> 1) & 3)) & 3;
    const unsigned short* gA0 = Xbf + (size_t)(m0 + row0) * H_ + kc0 * 8;
    const unsigned short* gA1 = Xbf + (size_t)(m0 + row1) * H_ + kc1 * 8;
    const unsigned short* gB0 = WT  + (size_t)(n0 + row0) * H_ + kc0 * 8;
    const unsigned short* gB1 = WT  + (size_t)(n0 + row1) * H_ + kc1 * 8;
    unsigned short* lA0 = As + idx0 * 8;
    unsigned short* lA1 = As + idx1 * 8;
    unsigned short* lB0 = Bs + idx0 * 8;
    unsigned short* lB1 = Bs + idx1 * 8;

    // fragment read: row = wtile + i*16 + fr, want kc = fq
    //   -> slot = (fq + (fr>>1)) & 3   (tile offsets ≡ 0 mod 8)
    int slotR = (fq + ((fr >> 1) & 3)) & 3;
    const bf16x8* pa[4];
    const bf16x8* pb[4];
#pragma unroll
    for (int i2 = 0; i2 < 4; ++i2)
        pa[i2] = (const bf16x8*)(As + ((wm * 64 + i2 * 16 + fr) * 4 + slotR) * 8);
#pragma unroll
    for (int j2 = 0; j2 < 4; ++j2)
        pb[j2] = (const bf16x8*)(Bs + ((wn * 64 + j2 * 16 + fr) * 4 + slotR) * 8);

    for (int k0 = 0; k0 < H_; k0 += 32) {
        __builtin_amdgcn_global_load_lds((const __attribute__((address_space(1))) void*)(gA0 + k0),
                                         (__attribute__((address_space(3))) void*)lA0, 16, 0, 0);
        __builtin_amdgcn_global_load_lds((const __attribute__((address_space(1))) void*)(gA1 + k0),
                                         (__attribute__((address_space(3))) void*)lA1, 16, 0, 0);
        __builtin_amdgcn_global_load_lds((const __attribute__((address_space(1))) void*)(gB0 + k0),
                                         (__attribute__((address_space(3))) void*)lB0, 16, 0, 0);
        __builtin_amdgcn_global_load_lds((const __attribute__((address_space(1))) void*)(gB1 + k0),
                                         (__attribute__((address_space(3))) void*)lB1, 16, 0, 0);
        __syncthreads();   // drains vmcnt (staging complete)
        bf16x8 af[4], bg[4];
#pragma unroll
        for (int i2 = 0; i2 < 4; ++i2) af[i2] = *pa[i2];
#pragma unroll
        for (int j2 = 0; j2 < 4; ++j2) bg[j2] = *pb[j2];
#pragma unroll
        for (int i2 = 0; i2 < 4; ++i2)
#pragma unroll
            for (int j2 = 0; j2 < 4; ++j2)
                acc[i2][j2] = __builtin_amdgcn_mfma_f32_16x16x32_bf16(af[i2], bg[j2], acc[i2][j2], 0, 0, 0);
        __syncthreads();   // protect LDS before next stage overwrites
    }

    // epilogue: tanh, weight by v, reduce 128 columns of this block
    int b   = m0 >> 11;            // 2048 rows per batch; tiles never straddle b
    int hop = n0 >> 10;
    float vv[4];
#pragma unroll
    for (int j2 = 0; j2 < 4; ++j2)
        vv[j2] = vcat[b * 2048 + n0 + wn * 64 + j2 * 16 + fr];

#pragma unroll
    for (int i2 = 0; i2 < 4; ++i2) {
#pragma unroll
        for (int r = 0; r < 4; ++r) {
            float sum = fast_tanh(acc[i2][0][r]) * vv[0]
                      + fast_tanh(acc[i2][1][r]) * vv[1]
                      + fast_tanh(acc[i2][2][r]) * vv[2]
                      + fast_tanh(acc[i2][3][r]) * vv[3];
            sum += __shfl_xor(sum, 1);
            sum += __shfl_xor(sum, 2);
            sum += __shfl_xor(sum, 4);
            sum += __shfl_xor(sum, 8);
            if (fr == 0) {
                int row = m0 + wm * 64 + i2 * 16 + fq * 4 + r;
                atomicAdd(&U[(size_t)hop * M_TOT + row], sum);
            }
        }
    }
}

// ---------------------------------------------------------------------------
// Kernel 5: softmax over s per (b,hop).  grid 64, block 256.
// ---------------------------------------------------------------------------
__global__ void k_softmax(const float* __restrict__ U, float* __restrict__ alpha) {
    int id  = blockIdx.x;
    int hop = id >> 5, b = id & 31;
    int t = threadIdx.x;
    const float* u = U + (size_t)hop * M_TOT + (size_t)b * S_;
    float* al = alpha + (size_t)hop * M_TOT + (size_t)b * S_;
    float v[8];
    float mx = -1e30f;
#pragma unroll
    for (int i = 0; i < 8; ++i) { v[i] = u[t + i * 256]; mx = fmaxf(mx, v[i]); }
    __shared__ float red[256];
    red[t] = mx; __syncthreads();
    for (int s = 128; s > 0; s >>= 1) {
        if (t < s) red[t] = fmaxf(red[t], red[t + s]);
        __syncthreads();
    }
    mx = red[0]; __syncthreads();
    float sum = 0.f;
#pragma unroll
    for (int i = 0; i < 8; ++i) { v[i] = expf(v[i] - mx); sum += v[i]; }
    red[t] = sum; __syncthreads();
    for (int s = 128; s > 0; s >>= 1) {
        if (t < s) red[t] += red[t + s];
        __syncthreads();
    }
    float inv = 1.0f / red[0];
#pragma unroll
    for (int i = 0; i < 8; ++i) al[t + i * 256] = v[i] * inv;
}

// ---------------------------------------------------------------------------
// Kernel 6: u_att = sum_s inputs[b,s,:] * alpha[b,s]. grid (32 b, 64 sc of 32),
// block 256 (round-2 proven config: 8 waves/CU latency hiding).
// ---------------------------------------------------------------------------
__global__ void k_wsum(const unsigned short* __restrict__ Xbf,
                       const float* __restrict__ alpha,
                       float* __restrict__ out1 /* pre-zeroed */,
                       float* __restrict__ out2 /* pre-zeroed */) {
    int b  = blockIdx.x;
    int sc = blockIdx.y;
    int t  = threadIdx.x;
    __shared__ float a1[32], a2[32];
    int s0 = sc * 32;
    if (t < 32)       a1[t]      = alpha[(size_t)b * S_ + s0 + t];
    else if (t < 64)  a2[t - 32] = alpha[(size_t)M_TOT + (size_t)b * S_ + s0 + (t - 32)];
    __syncthreads();
    const ushort4* xr = (const ushort4*)(Xbf + ((size_t)b * S_ + s0) * H_);
    float x0a = 0.f, x1a = 0.f, x2a = 0.f, x3a = 0.f;
    float x0b = 0.f, x1b = 0.f, x2b = 0.f, x3b = 0.f;
    for (int s = 0; s < 32; ++s) {
        ushort4 u = xr[(size_t)s * 256 + t];
        float f0 = bf2f(u.x), f1 = bf2f(u.y), f2 = bf2f(u.z), f3 = bf2f(u.w);
        float w1 = a1[s], w2 = a2[s];
        x0a += f0 * w1; x1a += f1 * w1; x2a += f2 * w1; x3a += f3 * w1;
        x0b += f0 * w2; x1b += f1 * w2; x2b += f2 * w2; x3b += f3 * w2;
    }
    float* o1 = out1 + b * H_ + t * 4;
    float* o2 = out2 + b * H_ + t * 4;
    atomicAdd(o1 + 0, x0a); atomicAdd(o1 + 1, x1a);
    atomicAdd(o1 + 2, x2a); atomicAdd(o1 + 3, x3a);
    atomicAdd(o2 + 0, x0b); atomicAdd(o2 + 1, x1b);
    atomicAdd(o2 + 2, x2b); atomicAdd(o2 + 3, x3b);
}

// ---------------------------------------------------------------------------
extern "C" void kernel_launch(void* const* d_in, const int* in_sizes, int n_in,
                              void* d_out, int out_size, void* d_ws, size_t ws_size,
                              hipStream_t stream) {
    const float* inputs = (const float*)d_in[0];
    const float* q      = (const float*)d_in[1];
    const float* W1     = (const float*)d_in[2];
    const float* Wm1    = (const float*)d_in[3];
    const float* Wh1    = (const float*)d_in[4];
    const float* W2     = (const float*)d_in[5];
    const float* Wm2    = (const float*)d_in[6];
    const float* Wh2    = (const float*)d_in[7];
    float* out = (float*)d_out;     // [3,B,H]: mean | u_att1 | u_att2

    // workspace layout (bytes); total ~133.8 MiB
    char* ws = (char*)d_ws;
    unsigned short* Xbf  = (unsigned short*)(ws);                 // 134217728 B
    unsigned short* WT   = (unsigned short*)(ws + 134217728);     //   4194304 B
    float*          vcat = (float*)(ws + 138412032);              //    262144 B
    float*          U    = (float*)(ws + 138674176);              //    524288 B
    float*          alph = (float*)(ws + 139198464);              //    524288 B
    float*          vtmp = (float*)(ws + 139722752);              //    262144 B

    hipMemsetAsync(d_out, 0, (size_t)out_size * sizeof(float), stream);
    // zero U + alph + vtmp in one shot (contiguous region)
    hipMemsetAsync(U, 0, 524288 + 524288 + 262144, stream);

    k_meanconv<<<dim3(32, 64),    256, 0, stream>>>(inputs, Xbf, out);
    k_wconv  <<<dim3(16, 16, 2),  256, 0, stream>>>(W1, W2, WT);
    k_vpart  <<<dim3(32, 2, 8),   256, 0, stream>>>(out, q, Wm1, Wm2, vtmp);
    k_vfin   <<<dim3(256),        256, 0, stream>>>(vtmp, Wh1, Wh2, vcat);
    k_gemm   <<<dim3(8192),       256, 0, stream>>>(Xbf, WT, vcat, U);
    k_softmax<<<dim3(64),         256, 0, stream>>>(U, alph);
    k_wsum   <<<dim3(32, 64),     256, 0, stream>>>(Xbf, alph, out + 32768, out + 65536);
}